// Round 5
// baseline (110.276 us; speedup 1.0000x reference)
//
#include <hip/hip_runtime.h>
#include <hip/hip_bf16.h>

#define NN   102      // nodes
#define NE   83       // edges in baked list (pre-filter)
#define NPAD 128      // padded node count

using bf16x8 = __attribute__((ext_vector_type(8))) short;   // 8 bf16 (4 VGPRs)
using f32x4  = __attribute__((ext_vector_type(4))) float;   // MFMA C/D

__device__ __constant__ int EDGES_C[NE * 2] = {
    0,6, 0,5, 6,8, 5,7, 0,62, 62,63, 63,64, 59,64, 59,60, 60,61, 61,62,
    0,74, 71,72, 72,73, 73,74, 74,75, 75,76, 76,77, 77,78, 78,79, 79,80,
    80,81, 81,82, 71,82, 71,83, 77,87, 83,84, 84,85, 85,86, 86,87, 87,88,
    88,89, 89,90, 83,90, 0,65, 65,66, 66,67, 67,68, 68,69, 69,70, 65,70,
    7,91, 91,92, 92,93, 93,94, 94,95, 91,96, 96,97, 97,98, 98,99, 91,100,
    100,101, 101,102, 102,103, 91,104, 104,105, 105,106, 106,107, 91,108,
    108,109, 109,110, 110,111, 8,112, 112,113, 113,114, 114,115, 115,116,
    112,117, 117,118, 118,119, 119,120, 112,121, 121,122, 122,123, 123,124,
    112,125, 125,126, 126,127, 127,128, 112,129, 129,130, 130,131, 131,132
};

// ws layout (bytes)
#define WS_BFRAG 0                   // 16 frags * 64 lanes * 16B = 16384
#define WS_OFF   16384               // 103 ints (padded to 512)
#define WS_ER    (16384 + 512)       // up to 256 ints
#define WS_EN    (16384 + 512 + 1024)// up to 256 floats

__device__ inline unsigned short f2bf(float f) {
  union { float f; unsigned u; } v; v.f = f;
  unsigned r = v.u + 0x7fffu + ((v.u >> 16) & 1u);   // RNE
  return (unsigned short)(r >> 16);
}

__device__ inline unsigned cvt_pk_bf16(float lo, float hi) {
  unsigned r;
  asm("v_cvt_pk_bf16_f32 %0, %1, %2" : "=v"(r) : "v"(lo), "v"(hi));
  return r;
}

// Block 0: normalized-graph CSR. Block 1: per-lane bf16 Wp^T fragments.
// Fragment f = mt*2+kc: lane holds Wp[k][e], e = mt*16+(lane&15),
// k = kc*32 + (lane>>4)*8 + i  -- the MFMA A-operand (out^T = Wp^T * act^T).
__global__ void gnn_setup(const float* __restrict__ Wp, char* __restrict__ ws) {
  const int t = threadIdx.x;

  if (blockIdx.x != 0) {               // independent: B-fragment bake
    unsigned short* bf = (unsigned short*)(ws + WS_BFRAG);
    for (int idx = t; idx < 16 * 64; idx += 256) {
      int lane = idx & 63;
      int f    = idx >> 6;             // f = mt*2 + kc
      int mt   = f >> 1, kc = f & 1;
      int e    = mt * 16 + (lane & 15);
      int kb   = kc * 32 + (lane >> 4) * 8;
      unsigned short* dst = bf + idx * 8;
#pragma unroll
      for (int i = 0; i < 8; ++i) dst[i] = f2bf(Wp[(kb + i) * 128 + e]);
    }
    return;
  }

  __shared__ float s_dinv[NN];
  __shared__ int   s_cnt[NN];
  __shared__ int   s_off[NN + 1];

  if (t < NN) {
    int deg = 1, cnt = 1;                       // self loop
    for (int e = 0; e < NE; ++e) {
      int r = EDGES_C[2*e], c = EDGES_C[2*e+1];
      if (r < NN && c == t) { ++deg; ++cnt; }
    }
    s_dinv[t] = 1.0f / sqrtf((float)deg);
    s_cnt[t]  = cnt;
  }
  __syncthreads();
  if (t < NN) {
    int o = 0;
    for (int c = 0; c < t; ++c) o += s_cnt[c];
    s_off[t] = o;
    if (t == NN - 1) s_off[NN] = o + s_cnt[t];
  }
  __syncthreads();
  int*   off = (int*)(ws + WS_OFF);
  int*   er  = (int*)(ws + WS_ER);
  float* en  = (float*)(ws + WS_EN);
  if (t < NN) {
    int c = t, pos = s_off[c];
    float dc = s_dinv[c];
    er[pos] = c; en[pos] = dc * dc; ++pos;      // self loop
    for (int e = 0; e < NE; ++e) {
      int r = EDGES_C[2*e], cc = EDGES_C[2*e+1];
      if (r < NN && cc == c) { er[pos] = r; en[pos] = s_dinv[r] * dc; ++pos; }
    }
    off[c] = s_off[c];
    if (c == 0) off[NN] = s_off[NN];
  }
}

// ONE WAVE = ONE BATCH ELEMENT; waves independent after one startup barrier.
// Swapped-operand MFMA: D = Wp^T(16e x 32k) * act^T(32k x 16node) -> out^T tile.
// C/D (m89): lane holds D[e = mt*16+(lane>>4)*4+j][node = nt*16+(lane&15)].
// Software-pipelined epilogue: compute(nt) -> read+store(nt-1) -> write-slab(nt),
// so each tile's LDS round-trip latency hides under the next tile's compute.
__global__ __launch_bounds__(256) void gnn_main(
    const float* __restrict__ x, const float* __restrict__ Wg,
    const float* __restrict__ bg, const float* __restrict__ bp,
    const char* __restrict__ ws, float* __restrict__ out, int B) {
  const int t    = threadIdx.x;
  const int lane = t & 63;
  const int wv   = t >> 6;
  const int b    = blockIdx.x * 4 + wv;

  __shared__ float swg[128];
  __shared__ float sbg[64];
  __shared__ float sbp[128];
  __shared__ float sxw[4][208];        // per-wave x slab
  __shared__ float syw[4][NPAD][2];    // per-wave y slab (zero-padded)
  __shared__ float st[4][16][132];     // per-wave transpose slab

  if (t < 128) { swg[t] = Wg[t]; sbp[t] = bp[t]; }
  if (t < 64)  sbg[t] = bg[t];
  __syncthreads();                     // the only block-wide barrier

  if (b >= B) return;

  float* sx = sxw[wv];
  float (*sy)[2] = syw[wv];

  // per-wave x load: 51 lanes x 16B = 204 floats (16B-aligned: 204*4 = 51*16)
  if (lane < 51)
    *(f32x4*)&sx[lane * 4] = *(const f32x4*)(x + (size_t)b * 204 + lane * 4);

  // y = S @ xn[b]; lane covers nodes (lane) and (lane+64); pad rows zeroed.
  {
    const int*   off = (const int*)(ws + WS_OFF);
    const int*   er  = (const int*)(ws + WS_ER);
    const float* en  = (const float*)(ws + WS_EN);
#pragma unroll
    for (int half = 0; half < 2; ++half) {
      const int n = lane + half * 64;
      float y0 = 0.f, y1 = 0.f;
      if (n < NN) {
        int s = off[n], e2 = off[n + 1];
        for (int j = s; j < e2; ++j) {
          int r = er[j]; float w = en[j];
          y0 = fmaf(w, sx[2 * r],     y0);
          y1 = fmaf(w, sx[2 * r + 1], y1);
        }
      }
      sy[n][0] = y0; sy[n][1] = y1;
    }
  }

  const int l15 = lane & 15;
  const int lhi = lane >> 4;
  const int kb  = lhi * 8;     // k offset within a 32-wide kc chunk
  const int rb  = lhi * 4;     // C/D row (=e) offset
  const int c32 = (lane & 31) * 4;
  const int rhi = lane >> 5;

  // Hoisted tile-invariant coefficients: Wg row0/row1 and b_gcn for this
  // lane's 16 k-values (12 ds_read_b128 once; zero per-tile LDS traffic).
  f32x4 WG0[2][2], WG1[2][2], BG[2][2];
#pragma unroll
  for (int kc = 0; kc < 2; ++kc)
#pragma unroll
    for (int h2 = 0; h2 < 2; ++h2) {
      WG0[kc][h2] = *(const f32x4*)&swg[kc * 32 + kb + 4 * h2];
      WG1[kc][h2] = *(const f32x4*)&swg[64 + kc * 32 + kb + 4 * h2];
      BG[kc][h2]  = *(const f32x4*)&sbg[kc * 32 + kb + 4 * h2];
    }
  // b_proj applied at the transpose-read (per-lane constant, 4 regs)
  const f32x4 bpv = *(const f32x4*)&sbp[c32];

  // A-operand: Wp^T fragments (block-invariant, L1/L2-resident), persistent
  const bf16x8* bfr = (const bf16x8*)(ws + WS_BFRAG);
  bf16x8 Apf[8][2];
#pragma unroll
  for (int mt = 0; mt < 8; ++mt) {
    Apf[mt][0] = bfr[(mt * 2 + 0) * 64 + lane];
    Apf[mt][1] = bfr[(mt * 2 + 1) * 64 + lane];
  }

  float* ob = out + (size_t)b * (NN * 128);

  f32x4 acc[8];

  auto compute_tile = [&](int nt) {
    const int node = nt * 16 + l15;
    const float y0 = sy[node][0], y1 = sy[node][1];
    bf16x8 Bact[2];
#pragma unroll
    for (int kc = 0; kc < 2; ++kc) {
      float v[8];
#pragma unroll
      for (int i = 0; i < 8; ++i) {
        float a = fmaf(y0, WG0[kc][i >> 2][i & 3],
                  fmaf(y1, WG1[kc][i >> 2][i & 3], BG[kc][i >> 2][i & 3]));
        v[i] = fmaxf(a, 0.f);
      }
      union { unsigned u[4]; bf16x8 f; } pk;
      pk.u[0] = cvt_pk_bf16(v[0], v[1]);
      pk.u[1] = cvt_pk_bf16(v[2], v[3]);
      pk.u[2] = cvt_pk_bf16(v[4], v[5]);
      pk.u[3] = cvt_pk_bf16(v[6], v[7]);
      Bact[kc] = pk.f;
    }
#pragma unroll
    for (int mt = 0; mt < 8; ++mt) { f32x4 z = {0.f,0.f,0.f,0.f}; acc[mt] = z; }
#pragma unroll
    for (int mt = 0; mt < 8; ++mt)
#pragma unroll
      for (int kc = 0; kc < 2; ++kc)
        acc[mt] = __builtin_amdgcn_mfma_f32_16x16x32_bf16(
            Apf[mt][kc], Bact[kc], acc[mt], 0, 0, 0);
  };

  auto write_slab = [&]() {
#pragma unroll
    for (int mt = 0; mt < 8; ++mt)
      *(f32x4*)&st[wv][l15][mt * 16 + rb] = acc[mt];
  };

  auto read_store = [&](int nt, int rows) {
#pragma unroll
    for (int pass = 0; pass < 8; ++pass) {
      const int n2 = pass * 2 + rhi;
      if (n2 < rows) {
        f32x4 row = *(const f32x4*)&st[wv][n2][c32];
        row = row + bpv;
        *(f32x4*)(ob + (nt * 16 + n2) * 128 + c32) = row;
      }
    }
  };

  compute_tile(0);
  write_slab();
#pragma unroll
  for (int nt = 1; nt < 7; ++nt) {
    compute_tile(nt);        // regs only; slab still holds nt-1
    read_store(nt - 1, 16);  // reads trail prior writes by a full compute phase
    write_slab();            // in-order per-wave LDS: safe WAR with the reads
  }
  read_store(6, NN - 96);    // 6 tail rows
}

extern "C" void kernel_launch(void* const* d_in, const int* in_sizes, int n_in,
                              void* d_out, int out_size, void* d_ws, size_t ws_size,
                              hipStream_t stream) {
  const float* x  = (const float*)d_in[0];   // (B, 204)
  const float* Wg = (const float*)d_in[1];   // (2, 64)
  const float* bg = (const float*)d_in[2];   // (64,)
  const float* Wp = (const float*)d_in[3];   // (64, 128)
  const float* bp = (const float*)d_in[4];   // (128,)
  float* out = (float*)d_out;                // (B, 102, 128)
  const int B = in_sizes[0] / 204;

  gnn_setup<<<2, 256, 0, stream>>>(Wp, (char*)d_ws);
  gnn_main<<<(B + 3) / 4, 256, 0, stream>>>(x, Wg, bg, bp, (const char*)d_ws, out, B);
}

// Round 6
// 101.931 us; speedup vs baseline: 1.0819x; 1.0819x over previous
//
#include <hip/hip_runtime.h>
#include <hip/hip_bf16.h>

#define NN   102      // nodes
#define NE   83       // edges in baked list (pre-filter)
#define NPAD 128      // padded node count

using bf16x8 = __attribute__((ext_vector_type(8))) short;   // 8 bf16 (4 VGPRs)
using f32x4  = __attribute__((ext_vector_type(4))) float;   // MFMA C/D

__device__ __constant__ int EDGES_C[NE * 2] = {
    0,6, 0,5, 6,8, 5,7, 0,62, 62,63, 63,64, 59,64, 59,60, 60,61, 61,62,
    0,74, 71,72, 72,73, 73,74, 74,75, 75,76, 76,77, 77,78, 78,79, 79,80,
    80,81, 81,82, 71,82, 71,83, 77,87, 83,84, 84,85, 85,86, 86,87, 87,88,
    88,89, 89,90, 83,90, 0,65, 65,66, 66,67, 67,68, 68,69, 69,70, 65,70,
    7,91, 91,92, 92,93, 93,94, 94,95, 91,96, 96,97, 97,98, 98,99, 91,100,
    100,101, 101,102, 102,103, 91,104, 104,105, 105,106, 106,107, 91,108,
    108,109, 109,110, 110,111, 8,112, 112,113, 113,114, 114,115, 115,116,
    112,117, 117,118, 118,119, 119,120, 112,121, 121,122, 122,123, 123,124,
    112,125, 125,126, 126,127, 127,128, 112,129, 129,130, 130,131, 131,132
};

// ws layout (bytes)
#define WS_BFRAG 0                   // 16 frags * 64 lanes * 16B = 16384
#define WS_OFF   16384               // 103 ints (padded to 512)
#define WS_ER    (16384 + 512)       // up to 256 ints
#define WS_EN    (16384 + 512 + 1024)// up to 256 floats

__device__ inline unsigned short f2bf(float f) {
  union { float f; unsigned u; } v; v.f = f;
  unsigned r = v.u + 0x7fffu + ((v.u >> 16) & 1u);   // RNE
  return (unsigned short)(r >> 16);
}

__device__ inline unsigned cvt_pk_bf16(float lo, float hi) {
  unsigned r;
  asm("v_cvt_pk_bf16_f32 %0, %1, %2" : "=v"(r) : "v"(lo), "v"(hi));
  return r;
}

// Block 0: normalized-graph CSR. Block 1: per-lane bf16 Wp^T fragments.
// Fragment f = mt*2+kc: lane holds Wp[k][e], e = mt*16+(lane&15),
// k = kc*32 + (lane>>4)*8 + i  -- the MFMA A-operand (out^T = Wp^T * act^T).
__global__ void gnn_setup(const float* __restrict__ Wp, char* __restrict__ ws) {
  const int t = threadIdx.x;

  if (blockIdx.x != 0) {               // independent: B-fragment bake
    unsigned short* bf = (unsigned short*)(ws + WS_BFRAG);
    for (int idx = t; idx < 16 * 64; idx += 256) {
      int lane = idx & 63;
      int f    = idx >> 6;             // f = mt*2 + kc
      int mt   = f >> 1, kc = f & 1;
      int e    = mt * 16 + (lane & 15);
      int kb   = kc * 32 + (lane >> 4) * 8;
      unsigned short* dst = bf + idx * 8;
#pragma unroll
      for (int i = 0; i < 8; ++i) dst[i] = f2bf(Wp[(kb + i) * 128 + e]);
    }
    return;
  }

  __shared__ float s_dinv[NN];
  __shared__ int   s_cnt[NN];
  __shared__ int   s_off[NN + 1];

  if (t < NN) {
    int deg = 1, cnt = 1;                       // self loop
    for (int e = 0; e < NE; ++e) {
      int r = EDGES_C[2*e], c = EDGES_C[2*e+1];
      if (r < NN && c == t) { ++deg; ++cnt; }
    }
    s_dinv[t] = 1.0f / sqrtf((float)deg);
    s_cnt[t]  = cnt;
  }
  __syncthreads();
  if (t < NN) {
    int o = 0;
    for (int c = 0; c < t; ++c) o += s_cnt[c];
    s_off[t] = o;
    if (t == NN - 1) s_off[NN] = o + s_cnt[t];
  }
  __syncthreads();
  int*   off = (int*)(ws + WS_OFF);
  int*   er  = (int*)(ws + WS_ER);
  float* en  = (float*)(ws + WS_EN);
  if (t < NN) {
    int c = t, pos = s_off[c];
    float dc = s_dinv[c];
    er[pos] = c; en[pos] = dc * dc; ++pos;      // self loop
    for (int e = 0; e < NE; ++e) {
      int r = EDGES_C[2*e], cc = EDGES_C[2*e+1];
      if (r < NN && cc == c) { er[pos] = r; en[pos] = s_dinv[r] * dc; ++pos; }
    }
    off[c] = s_off[c];
    if (c == 0) off[NN] = s_off[NN];
  }
}

// ONE WAVE = ONE BATCH ELEMENT; waves independent after one startup barrier.
// Swapped-operand MFMA: D = Wp^T(16e x 32k) * act^T(32k x 16node) -> out^T tile.
// C/D (m89): lane holds D[e = mt*16+(lane>>4)*4+j][node = nt*16+(lane&15)].
// Per-wave LDS transpose -> every global store = 1KB contiguous (2 full rows),
// issued NON-TEMPORAL to bypass L2 write-allocate (output is never re-read).
__global__ __launch_bounds__(256) void gnn_main(
    const float* __restrict__ x, const float* __restrict__ Wg,
    const float* __restrict__ bg, const float* __restrict__ bp,
    const char* __restrict__ ws, float* __restrict__ out, int B) {
  const int t    = threadIdx.x;
  const int lane = t & 63;
  const int wv   = t >> 6;
  const int b    = blockIdx.x * 4 + wv;

  __shared__ float swg[128];
  __shared__ float sbg[64];
  __shared__ float sbp[128];
  __shared__ float sxw[4][208];        // per-wave x slab
  __shared__ float syw[4][NPAD][2];    // per-wave y slab (zero-padded)
  __shared__ float st[4][16][132];     // per-wave transpose slab

  if (t < 128) { swg[t] = Wg[t]; sbp[t] = bp[t]; }
  if (t < 64)  sbg[t] = bg[t];
  __syncthreads();                     // the only block-wide barrier

  if (b >= B) return;

  float* sx = sxw[wv];
  float (*sy)[2] = syw[wv];

  // per-wave x load: 51 lanes x 16B = 204 floats
  if (lane < 51)
    *(f32x4*)&sx[lane * 4] = *(const f32x4*)(x + (size_t)b * 204 + lane * 4);

  // y = S @ xn[b]; lane covers nodes (lane) and (lane+64); pad rows zeroed.
  {
    const int*   off = (const int*)(ws + WS_OFF);
    const int*   er  = (const int*)(ws + WS_ER);
    const float* en  = (const float*)(ws + WS_EN);
#pragma unroll
    for (int half = 0; half < 2; ++half) {
      const int n = lane + half * 64;
      float y0 = 0.f, y1 = 0.f;
      if (n < NN) {
        int s = off[n], e2 = off[n + 1];
        for (int j = s; j < e2; ++j) {
          int r = er[j]; float w = en[j];
          y0 = fmaf(w, sx[2 * r],     y0);
          y1 = fmaf(w, sx[2 * r + 1], y1);
        }
      }
      sy[n][0] = y0; sy[n][1] = y1;
    }
  }

  const int l15 = lane & 15;
  const int lhi = lane >> 4;
  const int kb  = lhi * 8;     // k offset within a 32-wide kc chunk
  const int rb  = lhi * 4;     // C/D row (=e) offset
  const int c32 = (lane & 31) * 4;
  const int rhi = lane >> 5;

  // A-operand: Wp^T fragments (block-invariant, L1/L2-resident), persistent
  const bf16x8* bfr = (const bf16x8*)(ws + WS_BFRAG);
  bf16x8 Apf[8][2];
#pragma unroll
  for (int mt = 0; mt < 8; ++mt) {
    Apf[mt][0] = bfr[(mt * 2 + 0) * 64 + lane];
    Apf[mt][1] = bfr[(mt * 2 + 1) * 64 + lane];
  }
  // bias as C-in
  f32x4 bias[8];
#pragma unroll
  for (int mt = 0; mt < 8; ++mt)
    bias[mt] = *(const f32x4*)&sbp[mt * 16 + rb];

  float* ob = out + (size_t)b * (NN * 128);

  for (int nt = 0; nt < 7; ++nt) {
    // B-operand: act^T fragment for node tile nt
    const int node = nt * 16 + l15;
    const float y0 = sy[node][0], y1 = sy[node][1];
    bf16x8 Bact[2];
#pragma unroll
    for (int kc = 0; kc < 2; ++kc) {
      float v[8];
#pragma unroll
      for (int i = 0; i < 8; ++i) {
        int h = kc * 32 + kb + i;
        float a = fmaf(y0, swg[h], fmaf(y1, swg[64 + h], sbg[h]));
        v[i] = fmaxf(a, 0.f);
      }
      union { unsigned u[4]; bf16x8 f; } pk;
      pk.u[0] = cvt_pk_bf16(v[0], v[1]);
      pk.u[1] = cvt_pk_bf16(v[2], v[3]);
      pk.u[2] = cvt_pk_bf16(v[4], v[5]);
      pk.u[3] = cvt_pk_bf16(v[6], v[7]);
      Bact[kc] = pk.f;
    }

    f32x4 acc[8];
#pragma unroll
    for (int mt = 0; mt < 8; ++mt) acc[mt] = bias[mt];
#pragma unroll
    for (int mt = 0; mt < 8; ++mt)
#pragma unroll
      for (int kc = 0; kc < 2; ++kc)
        acc[mt] = __builtin_amdgcn_mfma_f32_16x16x32_bf16(
            Apf[mt][kc], Bact[kc], acc[mt], 0, 0, 0);

    // transpose through private slab
#pragma unroll
    for (int mt = 0; mt < 8; ++mt)
      *(f32x4*)&st[wv][l15][mt * 16 + rb] = acc[mt];

    const int rows = (nt < 6) ? 16 : (NN - 96);   // 16 or 6
#pragma unroll
    for (int pass = 0; pass < 8; ++pass) {
      const int n2 = pass * 2 + rhi;
      if (n2 < rows) {
        f32x4 row = *(const f32x4*)&st[wv][n2][c32];
        __builtin_nontemporal_store(row,
            (f32x4*)(ob + (nt * 16 + n2) * 128 + c32));
      }
    }
  }
}

extern "C" void kernel_launch(void* const* d_in, const int* in_sizes, int n_in,
                              void* d_out, int out_size, void* d_ws, size_t ws_size,
                              hipStream_t stream) {
  const float* x  = (const float*)d_in[0];   // (B, 204)
  const float* Wg = (const float*)d_in[1];   // (2, 64)
  const float* bg = (const float*)d_in[2];   // (64,)
  const float* Wp = (const float*)d_in[3];   // (64, 128)
  const float* bp = (const float*)d_in[4];   // (128,)
  float* out = (float*)d_out;                // (B, 102, 128)
  const int B = in_sizes[0] / 204;

  gnn_setup<<<2, 256, 0, stream>>>(Wp, (char*)d_ws);
  gnn_main<<<(B + 3) / 4, 256, 0, stream>>>(x, Wg, bg, bp, (const char*)d_ws, out, B);
}